// Round 19
// baseline (31.937 us; speedup 1.0000x reference)
//
#include <hip/hip_runtime.h>
#include <hip/hip_bf16.h>

#define EPS 1e-8f

#define BB 16
#define CC 256
#define TT 512
#define LL 4096
#define KC  32    // t-chunk
#define TCB 128   // c-tile
#define TLB 64    // l-tile -> 2048 blocks = 2 residency rounds at 4/CU
#define NW  (LL / TLB)   // 64 windows per batch
#define XR  40    // ws row stride in ushorts

typedef __attribute__((ext_vector_type(8))) short short8;
typedef __attribute__((ext_vector_type(4))) float f32x4;

__device__ __forceinline__ unsigned short bfbits(float f) {
    __hip_bfloat16 h = __float2bfloat16(f);
    return *(unsigned short*)&h;
}
__device__ __forceinline__ unsigned int pack2(float lo, float hi) {
    return (unsigned int)bfbits(lo) | ((unsigned int)bfbits(hi) << 16);
}

// ---------------------------------------------------------------------------
// Kernel A (tiny, 16 blocks): per-batch scan -> cen/nh tables AND per-window
// band bounds tmn/tmx (each t updates only the ~3 windows it touches).
// ---------------------------------------------------------------------------
__global__ __launch_bounds__(512)
void scan_kernel(const float* __restrict__ w,
                 const float* __restrict__ sigma_scale,
                 float* __restrict__ cenG,
                 float* __restrict__ nhG,
                 int* __restrict__ tmnG,
                 int* __restrict__ tmxG) {
    const int b = blockIdx.x;
    const int t = threadIdx.x;       // 512
    const int lane = t & 63;
    const int wid  = t >> 6;
    __shared__ float part[8], offs[8];

    if (t < NW) { tmnG[b * NW + t] = TT; tmxG[b * NW + t] = -1; }

    const float wv = w[b * TT + t];
    float v = wv;
#pragma unroll
    for (int o = 1; o < 64; o <<= 1) {
        float u = __shfl_up(v, o);
        if (lane >= o) v += u;
    }
    if (lane == 63) part[wid] = v;
    __syncthreads();                 // part[] + bound init visible
    if (t == 0) {
        float run = 0.0f;
#pragma unroll
        for (int i = 0; i < 8; ++i) { offs[i] = run; run += part[i]; }
    }
    __syncthreads();
    const float cum = offs[wid] + v;
    const float ss  = sigma_scale[0];
    const float sg  = wv * ss;
    const float cen = cum - 0.5f * wv;
    const float rad = 6.5f * sg + 1.0f;   // cut terms <= e^-21
    cenG[b * TT + t] = cen;
    nhG[b * TT + t]  = -0.5f / (sg * sg + EPS);

    int wlo = (int)floorf((cen - rad) * (1.0f / TLB)) - 1;
    int whi = (int)floorf((cen + rad) * (1.0f / TLB)) + 1;
    if (wlo < 0) wlo = 0;
    if (whi > NW - 1) whi = NW - 1;
    for (int wi = wlo; wi <= whi; ++wi) {
        const float w0 = (float)(wi * TLB);
        const float w1 = w0 + (float)(TLB - 1);
        if (cen + rad >= w0 && cen - rad <= w1) {
            atomicMin(&tmnG[b * NW + wi], t);
            atomicMax(&tmxG[b * NW + wi], t);
        }
    }
}

// ---------------------------------------------------------------------------
// Kernel B: banded fused GEMM, 128c x 64l, 2048 blocks (2 residency rounds).
// Prologue: coalesced table load + 2 broadcast ints (band precomputed).
// Chunk loop: R14-proven double-buffered EXPW/MFMA, 1 barrier per chunk.
// ---------------------------------------------------------------------------

// 64l x 32t weight chunk: 8 exps/thread; l_loc=tid>>2, tg=tid&3
#define EXPW(tc_, buf_)                                                         \
    {                                                                           \
        const int t0 = (tc_) + tg * 8;                                          \
        const float4 cv0 = *(const float4*)&cen_s[t0];                          \
        const float4 cv1 = *(const float4*)&cen_s[t0 + 4];                      \
        const float4 nv0 = *(const float4*)&nh_s[t0];                           \
        const float4 nv1 = *(const float4*)&nh_s[t0 + 4];                       \
        const float4 xk0 = *(const float4*)&xm_s[t0];                           \
        const float4 xk1 = *(const float4*)&xm_s[t0 + 4];                       \
        const float posf = (float)(l0 + l_loc);                                 \
        float mu, e0, e1, e2, e3, e4, e5, e6, e7;                               \
        mu = posf - cv0.x; e0 = __expf(mu * mu * nv0.x);                        \
        mu = posf - cv0.y; e1 = __expf(mu * mu * nv0.y);                        \
        mu = posf - cv0.z; e2 = __expf(mu * mu * nv0.z);                        \
        mu = posf - cv0.w; e3 = __expf(mu * mu * nv0.w);                        \
        mu = posf - cv1.x; e4 = __expf(mu * mu * nv1.x);                        \
        mu = posf - cv1.y; e5 = __expf(mu * mu * nv1.y);                        \
        mu = posf - cv1.z; e6 = __expf(mu * mu * nv1.z);                        \
        mu = posf - cv1.w; e7 = __expf(mu * mu * nv1.w);                        \
        p += ((e0 + e1) + (e2 + e3)) + ((e4 + e5) + (e6 + e7));                 \
        uint4 pk;                                                               \
        pk.x = pack2(e0 * xk0.x, e1 * xk0.y);                                   \
        pk.y = pack2(e2 * xk0.z, e3 * xk0.w);                                   \
        pk.z = pack2(e4 * xk1.x, e5 * xk1.y);                                   \
        pk.w = pack2(e6 * xk1.z, e7 * xk1.w);                                   \
        *(uint4*)&ws[buf_][l_loc][tg * 8] = pk;                                 \
    }

#define AFRAG(AF, crow_, tc_)                                                   \
    {                                                                           \
        const float* xp = &x[xbase + (size_t)(crow_) * TT + (tc_) + lg * 8];    \
        const float4 a0 = *(const float4*)xp;                                   \
        const float4 a1 = *(const float4*)(xp + 4);                             \
        uint4 ap;                                                               \
        ap.x = pack2(a0.x, a0.y);                                               \
        ap.y = pack2(a0.z, a0.w);                                               \
        ap.z = pack2(a1.x, a1.y);                                               \
        ap.w = pack2(a1.z, a1.w);                                               \
        AF = *(short8*)&ap;                                                     \
    }

#define MFMA_STEP(buf_, tc_)                                                    \
    {                                                                           \
        short8 af0, af1;                                                        \
        AFRAG(af0, wid * 32 + lq, tc_);                                         \
        AFRAG(af1, wid * 32 + 16 + lq, tc_);                                    \
        _Pragma("unroll")                                                       \
        for (int n = 0; n < 4; ++n) {                                           \
            const short8 bfr = *(const short8*)&ws[buf_][n * 16 + lq][lg * 8];  \
            acc0[n] = __builtin_amdgcn_mfma_f32_16x16x32_bf16(af0, bfr, acc0[n], 0, 0, 0); \
            acc1[n] = __builtin_amdgcn_mfma_f32_16x16x32_bf16(af1, bfr, acc1[n], 0, 0, 0); \
        }                                                                       \
    }

__global__ __launch_bounds__(256, 4)
void fused_kernel(const float* __restrict__ x,
                  const float* __restrict__ x_mask,
                  const float* __restrict__ y_mask,
                  const float* __restrict__ cenG,
                  const float* __restrict__ nhG,
                  const int* __restrict__ tmnG,
                  const int* __restrict__ tmxG,
                  float* __restrict__ out) {
    __shared__ unsigned short ws[2][TLB][XR];        // 10.0 KB
    __shared__ float cen_s[TT], nh_s[TT], xm_s[TT];  // 6 KB
    __shared__ float dsum[TLB], sscale[TLB];

    // XCD-chunked bijective swizzle: 2048 blocks, XCD k -> batches 2k,2k+1.
    const int gid = blockIdx.x;
    const int lid = (gid & 7) * 256 + (gid >> 3);
    const int b   = lid >> 7;
    const int rr  = lid & 127;
    const int l0  = (rr >> 1) * TLB;
    const int c0  = (rr & 1) * TCB;

    const int tid  = threadIdx.x;
    const int lane = tid & 63;
    const int wid  = tid >> 6;
    const int lq   = lane & 15;
    const int lg   = lane >> 4;
    const int l_loc = tid >> 2;   // EXPW: 64 l's, 4 threads each
    const int tg    = tid & 3;    // EXPW: 4 t-slices of 8
    const int bTT  = b * TT;
    const size_t xbase = (size_t)(b * CC + c0) * TT;

    // ---- prologue: coalesced table load + broadcast band bounds ----
#pragma unroll
    for (int i = 0; i < 2; ++i) {
        const int tt = tid + 256 * i;
        cen_s[tt] = cenG[bTT + tt];
        nh_s[tt]  = nhG[bTT + tt];
        xm_s[tt]  = x_mask[bTT + tt];
    }
    const int widx = b * NW + (l0 / TLB);
    const int tmn = tmnG[widx];
    const int tmx = tmxG[widx];
    __syncthreads();

    int nch = 0, tlo = 0;
    if (tmx >= 0) {
        tlo = tmn & ~3;                          // float4 alignment
        nch = (tmx - tlo + KC) / KC;
        const int maxlo = TT - nch * KC;
        if (tlo > maxlo) tlo = maxlo;            // window end <= TT
    }

    f32x4 acc0[4], acc1[4];
#pragma unroll
    for (int n = 0; n < 4; ++n) { acc0[n] = (f32x4)0.0f; acc1[n] = (f32x4)0.0f; }
    float p = 0.0f;

    // ---- banded pipelined GEMM ----
    if (nch > 0) {
        EXPW(tlo, 0);
        __syncthreads();
        for (int i = 0; i < nch; ++i) {
            const int cur = i & 1;
            if (i + 1 < nch) EXPW(tlo + (i + 1) * KC, cur ^ 1);
            MFMA_STEP(cur, tlo + i * KC);
            __syncthreads();
        }
    }

    // ---- denominator: reduce p over the 4 t-slice threads per l ----
    p += __shfl_xor(p, 1);
    p += __shfl_xor(p, 2);
    if (tg == 0) dsum[l_loc] = p;
    __syncthreads();
    if (tid < TLB)
        sscale[tid] = y_mask[b * LL + l0 + tid] / (dsum[tid] + EPS);
    __syncthreads();

    // ---- epilogue: direct stores (R7-proven pattern) ----
    float sc[4];
#pragma unroll
    for (int n = 0; n < 4; ++n) sc[n] = sscale[n * 16 + lq];

    const size_t obase = (size_t)(b * CC + c0) * LL + l0;
#pragma unroll
    for (int r = 0; r < 4; ++r) {
        const int rowA = wid * 32 + lg * 4 + r;
        float* opA = &out[obase + (size_t)rowA * LL];
#pragma unroll
        for (int n = 0; n < 4; ++n) opA[n * 16 + lq] = acc0[n][r] * sc[n];
        float* opB = opA + 16 * LL;
#pragma unroll
        for (int n = 0; n < 4; ++n) opB[n * 16 + lq] = acc1[n][r] * sc[n];
    }
}

extern "C" void kernel_launch(void* const* d_in, const int* in_sizes, int n_in,
                              void* d_out, int out_size, void* d_ws, size_t ws_size,
                              hipStream_t stream) {
    const float* x           = (const float*)d_in[0];
    const float* w           = (const float*)d_in[1];
    const float* x_mask      = (const float*)d_in[2];
    const float* y_mask      = (const float*)d_in[3];
    const float* sigma_scale = (const float*)d_in[4];
    float* out = (float*)d_out;

    float* cenG = (float*)d_ws;
    float* nhG  = cenG + BB * TT;
    int*   tmnG = (int*)(nhG + BB * TT);
    int*   tmxG = tmnG + BB * NW;

    hipLaunchKernelGGL(scan_kernel, dim3(BB), dim3(512), 0, stream,
                       w, sigma_scale, cenG, nhG, tmnG, tmxG);
    hipLaunchKernelGGL(fused_kernel,
                       dim3((LL / TLB) * (CC / TCB) * BB), dim3(256), 0, stream,
                       x, x_mask, y_mask, cenG, nhG, tmnG, tmxG, out);
}

// Round 20
// 23.382 us; speedup vs baseline: 1.3658x; 1.3658x over previous
//
#include <hip/hip_runtime.h>
#include <hip/hip_bf16.h>

#define EPS 1e-8f

#define BB 16
#define CC 256
#define TT 512
#define LL 4096
#define KC  32    // t-chunk
#define TCB 128   // c-tile
#define TLB 128   // l-tile
#define XR  40    // ws row stride in ushorts (80B, 16B-aligned rows)
#define OBS 132   // epilogue LDS row stride in floats (528B, 16B-aligned)

typedef __attribute__((ext_vector_type(8))) short short8;
typedef __attribute__((ext_vector_type(4))) float f32x4;

__device__ __forceinline__ unsigned short bfbits(float f) {
    __hip_bfloat16 h = __float2bfloat16(f);
    return *(unsigned short*)&h;
}
__device__ __forceinline__ unsigned int pack2(float lo, float hi) {
    return (unsigned int)bfbits(lo) | ((unsigned int)bfbits(hi) << 16);
}

// ---------------------------------------------------------------------------
// Best-known kernel (R14): single fused kernel.
//   phase 0: per-block redundant scan of w[b,:] -> cen/nh/xm in LDS
//   phase 1: per-t band test (|mu| <= 6.5*sigma_t+1) -> [tlo, tlo+nch*KC)
//   phase 2: banded GEMM: A-frags from global x (L2-resident), W chunk in
//            double-buffered LDS (bf16), raw-exp partials -> denominator
//   phase 3: epilogue: scale, per-wave LDS transpose, NONTEMPORAL dwordx4
//            stores (full 128B lines stream to HBM; x stays in L2)
// Block: 128c x 128l, 256 thr = 4 waves (32c each). Grid: 1024 = 4/CU x 256.
// ---------------------------------------------------------------------------

#define EXPW(tc_, buf_)                                                         \
    {                                                                           \
        _Pragma("unroll")                                                       \
        for (int i_ = 0; i_ < 2; ++i_) {                                        \
            const int slot  = tid + 256 * i_;                                   \
            const int l_loc = slot >> 2;                                        \
            const int tg    = slot & 3;                                         \
            const int t0    = (tc_) + tg * 8;                                   \
            const float4 cv0 = *(const float4*)&cen_s[t0];                      \
            const float4 cv1 = *(const float4*)&cen_s[t0 + 4];                  \
            const float4 nv0 = *(const float4*)&nh_s[t0];                       \
            const float4 nv1 = *(const float4*)&nh_s[t0 + 4];                   \
            const float4 xk0 = *(const float4*)&xm_s[t0];                       \
            const float4 xk1 = *(const float4*)&xm_s[t0 + 4];                   \
            const float posf = (float)(l0 + l_loc);                             \
            float mu, e0, e1, e2, e3, e4, e5, e6, e7;                           \
            mu = posf - cv0.x; e0 = __expf(mu * mu * nv0.x);                    \
            mu = posf - cv0.y; e1 = __expf(mu * mu * nv0.y);                    \
            mu = posf - cv0.z; e2 = __expf(mu * mu * nv0.z);                    \
            mu = posf - cv0.w; e3 = __expf(mu * mu * nv0.w);                    \
            mu = posf - cv1.x; e4 = __expf(mu * mu * nv1.x);                    \
            mu = posf - cv1.y; e5 = __expf(mu * mu * nv1.y);                    \
            mu = posf - cv1.z; e6 = __expf(mu * mu * nv1.z);                    \
            mu = posf - cv1.w; e7 = __expf(mu * mu * nv1.w);                    \
            const float ps = ((e0 + e1) + (e2 + e3)) + ((e4 + e5) + (e6 + e7)); \
            if (i_ == 0) p0 += ps; else p1 += ps;                               \
            uint4 pk;                                                           \
            pk.x = pack2(e0 * xk0.x, e1 * xk0.y);                               \
            pk.y = pack2(e2 * xk0.z, e3 * xk0.w);                               \
            pk.z = pack2(e4 * xk1.x, e5 * xk1.y);                               \
            pk.w = pack2(e6 * xk1.z, e7 * xk1.w);                               \
            *(uint4*)&ws[buf_][l_loc][tg * 8] = pk;                             \
        }                                                                       \
    }

#define AFRAG(AF, crow_, tc_)                                                   \
    {                                                                           \
        const float* xp = &x[xbase + (size_t)(crow_) * TT + (tc_) + lg * 8];    \
        const float4 a0 = *(const float4*)xp;                                   \
        const float4 a1 = *(const float4*)(xp + 4);                             \
        uint4 ap;                                                               \
        ap.x = pack2(a0.x, a0.y);                                               \
        ap.y = pack2(a0.z, a0.w);                                               \
        ap.z = pack2(a1.x, a1.y);                                               \
        ap.w = pack2(a1.z, a1.w);                                               \
        AF = *(short8*)&ap;                                                     \
    }

#define MFMA_STEP(buf_, tc_)                                                    \
    {                                                                           \
        short8 af0, af1;                                                        \
        AFRAG(af0, wv * 32 + lq, tc_);                                          \
        AFRAG(af1, wv * 32 + 16 + lq, tc_);                                     \
        _Pragma("unroll")                                                       \
        for (int n = 0; n < 8; ++n) {                                           \
            const short8 bfr = *(const short8*)&ws[buf_][n * 16 + lq][lg * 8];  \
            acc0[n] = __builtin_amdgcn_mfma_f32_16x16x32_bf16(af0, bfr, acc0[n], 0, 0, 0); \
            acc1[n] = __builtin_amdgcn_mfma_f32_16x16x32_bf16(af1, bfr, acc1[n], 0, 0, 0); \
        }                                                                       \
    }

__global__ __launch_bounds__(256, 4)
void fused_kernel(const float* __restrict__ x,
                  const float* __restrict__ w,
                  const float* __restrict__ x_mask,
                  const float* __restrict__ y_mask,
                  const float* __restrict__ sigma_scale,
                  float* __restrict__ out) {
    __shared__ unsigned short ws[2][TLB][XR];        // 20.0 KB (reused by epilogue)
    __shared__ float cen_s[TT], nh_s[TT], xm_s[TT];  // 6 KB
    __shared__ float dsum[TLB], sscale[TLB];
    __shared__ float part[4], offs[4];
    __shared__ int tmin_s, tmax_s;

    // XCD-chunked bijective swizzle: 1024 blocks, XCD k -> batches 2k,2k+1.
    const int gid = blockIdx.x;
    const int lid = (gid & 7) * 128 + (gid >> 3);
    const int b   = lid >> 6;
    const int rr  = lid & 63;
    const int l0  = (rr >> 1) * TLB;
    const int c0  = (rr & 1) * TCB;

    const int tid  = threadIdx.x;
    const int lane = tid & 63;
    const int wid  = tid >> 6;   // wave id == c-subtile
    const int wv   = wid;
    const int lq   = lane & 15;
    const int lg   = lane >> 4;
    const int bTT  = b * TT;
    const size_t xbase = (size_t)(b * CC + c0) * TT;

    if (tid == 0) { tmin_s = TT; tmax_s = -1; }

    // ---- phase 0: fused scan (2 w elems per thread) ----
    const int t2 = tid * 2;
    const float2 w2  = *(const float2*)&w[bTT + t2];
    const float2 xm2 = *(const float2*)&x_mask[bTT + t2];
    const float ss = sigma_scale[0];
    const float pairsum = w2.x + w2.y;
    float v = pairsum;
#pragma unroll
    for (int o = 1; o < 64; o <<= 1) {
        float u = __shfl_up(v, o);
        if (lane >= o) v += u;
    }
    if (lane == 63) part[wid] = v;
    __syncthreads();                       // (A) part[] + tmin init visible
    if (tid == 0) {
        float run = 0.0f;
#pragma unroll
        for (int i = 0; i < 4; ++i) { offs[i] = run; run += part[i]; }
    }
    __syncthreads();                       // (B) offs[] visible
    const float base = offs[wid] + v - pairsum;   // exclusive prefix
    const float cum1 = base + w2.x;
    const float cum2 = cum1 + w2.y;
    const float cenA = cum1 - 0.5f * w2.x;
    const float cenB = cum2 - 0.5f * w2.y;
    cen_s[t2]     = cenA;
    cen_s[t2 + 1] = cenB;
    const float sgA = w2.x * ss, sgB = w2.y * ss;
    nh_s[t2]     = -0.5f / (sgA * sgA + EPS);
    nh_s[t2 + 1] = -0.5f / (sgB * sgB + EPS);
    xm_s[t2]     = xm2.x;
    xm_s[t2 + 1] = xm2.y;

    // ---- phase 1: per-t band test (cut terms <= e^-21, << eps) ----
    const float l0f = (float)l0;
    const float l1f = l0f + (float)(TLB - 1);
    const float rA = 6.5f * sgA + 1.0f;
    const float rB = 6.5f * sgB + 1.0f;
    if (cenA + rA >= l0f && cenA - rA <= l1f) {
        atomicMin(&tmin_s, t2); atomicMax(&tmax_s, t2);
    }
    if (cenB + rB >= l0f && cenB - rB <= l1f) {
        atomicMin(&tmin_s, t2 + 1); atomicMax(&tmax_s, t2 + 1);
    }
    __syncthreads();                       // (C) LDS tables + band ready
    const int tlo = tmin_s & ~(KC - 1);
    const int nch = (tmax_s >= 0) ? ((((tmax_s & ~(KC - 1)) + KC) - tlo) / KC) : 0;

    f32x4 acc0[8], acc1[8];
#pragma unroll
    for (int n = 0; n < 8; ++n) { acc0[n] = (f32x4)0.0f; acc1[n] = (f32x4)0.0f; }
    float p0 = 0.0f, p1 = 0.0f;

    // ---- phase 2: banded pipelined GEMM ----
    if (nch > 0) {
        EXPW(tlo, 0);
        __syncthreads();
        for (int i = 0; i < nch; ++i) {
            const int cur = i & 1;
            if (i + 1 < nch) EXPW(tlo + (i + 1) * KC, cur ^ 1);
            MFMA_STEP(cur, tlo + i * KC);
            __syncthreads();
        }
    }

    // ---- denominator: 4-lane groups share one l ----
    p0 += __shfl_xor(p0, 1); p0 += __shfl_xor(p0, 2);
    p1 += __shfl_xor(p1, 1); p1 += __shfl_xor(p1, 2);
    if ((tid & 3) == 0) {
        dsum[tid >> 2]        = p0;
        dsum[(tid >> 2) + 64] = p1;
    }
    __syncthreads();
    if (tid < TLB)
        sscale[tid] = y_mask[b * LL + l0 + tid] / (dsum[tid] + EPS);
    __syncthreads();   // sscale ready; all ws reads done -> safe to reuse ws

    // ---- phase 3: epilogue (LDS transpose -> full-line NT dwordx4) ----
    float sc[8];
#pragma unroll
    for (int n = 0; n < 8; ++n) sc[n] = sscale[n * 16 + lq];

    // per-wave private fp32 slab inside ws: 4 rows x OBS floats
    float* obuf = ((float*)ws) + wv * (4 * OBS);
    const size_t obase = (size_t)(b * CC + c0) * LL + l0;

#pragma unroll
    for (int half = 0; half < 2; ++half) {
#pragma unroll
        for (int r = 0; r < 4; ++r) {
            // scatter this row-group into LDS (row = lg, col = n*16+lq)
#pragma unroll
            for (int n = 0; n < 8; ++n) {
                const float val = (half ? acc1[n][r] : acc0[n][r]) * sc[n];
                obuf[lg * OBS + n * 16 + lq] = val;
            }
            // gather row-contiguous; NT dwordx4: wave covers 4 rows x 256B
            const int orow = wv * 32 + half * 16 + (lane >> 4) * 4 + r;
            float* op = &out[obase + (size_t)orow * LL];
            const f32x4 v0 = *(const f32x4*)&obuf[(lane >> 4) * OBS + (lane & 15) * 4];
            const f32x4 v1 = *(const f32x4*)&obuf[(lane >> 4) * OBS + 64 + (lane & 15) * 4];
            __builtin_nontemporal_store(v0, (f32x4*)(op + (lane & 15) * 4));
            __builtin_nontemporal_store(v1, (f32x4*)(op + 64 + (lane & 15) * 4));
        }
    }
}

extern "C" void kernel_launch(void* const* d_in, const int* in_sizes, int n_in,
                              void* d_out, int out_size, void* d_ws, size_t ws_size,
                              hipStream_t stream) {
    const float* x           = (const float*)d_in[0];
    const float* w           = (const float*)d_in[1];
    const float* x_mask      = (const float*)d_in[2];
    const float* y_mask      = (const float*)d_in[3];
    const float* sigma_scale = (const float*)d_in[4];
    float* out = (float*)d_out;

    hipLaunchKernelGGL(fused_kernel, dim3((LL / TLB) * (CC / TCB) * BB), dim3(256), 0, stream,
                       x, w, x_mask, y_mask, sigma_scale, out);
}